// Round 1
// baseline (198.070 us; speedup 1.0000x reference)
//
#include <hip/hip_runtime.h>
#include <hip/hip_bf16.h>

// DeepLinearNet: out = x @ (W_0^T W_1^T ... W_63^T), x:(8388608,3) fp32, W:(64,3,3) fp32.
// The 64-layer chain is collapsed into one 3x3 matrix P (computed in fp64 by a
// tiny kernel), then applied as a memory-bound streaming kernel.
// Numerics: chain is contractive (|out|max ~ 1.4e-5); fp64-collapsed P differs
// from the exact result by ~1e-12 abs, threshold is 2.9e-7 abs.

#define DEPTH 64

// ---- Kernel A: fold the 64 transposed 3x3 matrices into P (fp64), P -> ws ----
__global__ void fold_weights(const float* __restrict__ W, float* __restrict__ P) {
    if (threadIdx.x != 0 || blockIdx.x != 0) return;
    double M[3][3] = {{1.0, 0.0, 0.0}, {0.0, 1.0, 0.0}, {0.0, 0.0, 1.0}};
    for (int l = 0; l < DEPTH; ++l) {
        const float* Wl = W + l * 9;          // Wl[j][k] at Wl[j*3+k]
        double N[3][3];
        #pragma unroll
        for (int i = 0; i < 3; ++i) {
            #pragma unroll
            for (int j = 0; j < 3; ++j) {
                // M_new[i][j] = sum_k M[i][k] * (W_l^T)[k][j] = sum_k M[i][k] * Wl[j][k]
                N[i][j] = M[i][0] * (double)Wl[j * 3 + 0]
                        + M[i][1] * (double)Wl[j * 3 + 1]
                        + M[i][2] * (double)Wl[j * 3 + 2];
            }
        }
        #pragma unroll
        for (int i = 0; i < 3; ++i)
            #pragma unroll
            for (int j = 0; j < 3; ++j)
                M[i][j] = N[i][j];
    }
    #pragma unroll
    for (int i = 0; i < 3; ++i)
        #pragma unroll
        for (int j = 0; j < 3; ++j)
            P[i * 3 + j] = (float)M[i][j];    // P[k][j]: out_j = sum_k x_k * P[k*3+j]
}

// ---- Kernel B: out[i] = x[i] @ P, 4 rows (= 3 float4) per thread ----
__global__ __launch_bounds__(256) void apply_chain(
        const float4* __restrict__ x4, float4* __restrict__ o4,
        const float* __restrict__ P, long long n4) {
    const long long t = (long long)blockIdx.x * blockDim.x + threadIdx.x;
    const long long i0 = t * 3;
    if (i0 + 2 >= n4 + 0 && i0 >= n4) return;   // exact-fit grid; guard is dead code
    // P is a wave-uniform address -> scalar loads into SGPRs
    const float p00 = P[0], p01 = P[1], p02 = P[2];
    const float p10 = P[3], p11 = P[4], p12 = P[5];
    const float p20 = P[6], p21 = P[7], p22 = P[8];

    float4 a = x4[i0];
    float4 b = x4[i0 + 1];
    float4 c = x4[i0 + 2];

    // rows: r0=(a.x,a.y,a.z) r1=(a.w,b.x,b.y) r2=(b.z,b.w,c.x) r3=(c.y,c.z,c.w)
    float4 oa, ob, oc;
    // row 0 -> oa.x, oa.y, oa.z
    oa.x = fmaf(a.x, p00, fmaf(a.y, p10, a.z * p20));
    oa.y = fmaf(a.x, p01, fmaf(a.y, p11, a.z * p21));
    oa.z = fmaf(a.x, p02, fmaf(a.y, p12, a.z * p22));
    // row 1 -> oa.w, ob.x, ob.y
    oa.w = fmaf(a.w, p00, fmaf(b.x, p10, b.y * p20));
    ob.x = fmaf(a.w, p01, fmaf(b.x, p11, b.y * p21));
    ob.y = fmaf(a.w, p02, fmaf(b.x, p12, b.y * p22));
    // row 2 -> ob.z, ob.w, oc.x
    ob.z = fmaf(b.z, p00, fmaf(b.w, p10, c.x * p20));
    ob.w = fmaf(b.z, p01, fmaf(b.w, p11, c.x * p21));
    oc.x = fmaf(b.z, p02, fmaf(b.w, p12, c.x * p22));
    // row 3 -> oc.y, oc.z, oc.w
    oc.y = fmaf(c.y, p00, fmaf(c.z, p10, c.w * p20));
    oc.z = fmaf(c.y, p01, fmaf(c.z, p11, c.w * p21));
    oc.w = fmaf(c.y, p02, fmaf(c.z, p12, c.w * p22));

    o4[i0]     = oa;
    o4[i0 + 1] = ob;
    o4[i0 + 2] = oc;
}

extern "C" void kernel_launch(void* const* d_in, const int* in_sizes, int n_in,
                              void* d_out, int out_size, void* d_ws, size_t ws_size,
                              hipStream_t stream) {
    const float* x = (const float*)d_in[0];
    const float* W = (const float*)d_in[1];
    float* out = (float*)d_out;
    float* P = (float*)d_ws;                   // 9 floats of scratch

    fold_weights<<<1, 64, 0, stream>>>(W, P);

    const long long n_floats = (long long)in_sizes[0];   // 25165824
    const long long n4 = n_floats / 4;                   // 6291456 float4s
    const long long n_threads = n4 / 3;                  // 2097152 (exact)
    const int block = 256;
    const int grid = (int)((n_threads + block - 1) / block);   // 8192

    apply_chain<<<grid, block, 0, stream>>>(
        (const float4*)x, (float4*)out, P, n4);
}

// Round 2
// 180.213 us; speedup vs baseline: 1.0991x; 1.0991x over previous
//
#include <hip/hip_runtime.h>
#include <hip/hip_bf16.h>

// DeepLinearNet: out = x @ (W_0^T W_1^T ... W_63^T), x:(8388608,3) fp32, W:(64,3,3) fp32.
// Collapse the 64-layer chain into one 3x3 matrix P (fp64 tree-fold, ~3us),
// then apply P in a memory-bound streaming kernel with LDS-staged coalescing
// (dense 16B/lane load+store instructions; strided row access only in LDS).

#define DEPTH 64
#define BLOCK 256
#define CHUNK (BLOCK * 3)   // float4s per block = 768 (= 1024 rows)

// ---- Kernel A: parallel fold. 64 threads each load one W_l (one latency
// round), then a 6-step order-preserving product tree in LDS (fp64). ----
__global__ __launch_bounds__(64) void fold_weights(const float* __restrict__ W,
                                                   float* __restrict__ P) {
    __shared__ double M[DEPTH][9];
    const int t = threadIdx.x;  // 0..63, single wave
    // M_t = W_t^T  (row-major: M[t][k*3+j] = (W_t^T)[k][j] = W_t[j][k])
    const float* Wl = W + t * 9;
    #pragma unroll
    for (int k = 0; k < 3; ++k)
        #pragma unroll
        for (int j = 0; j < 3; ++j)
            M[t][k * 3 + j] = (double)Wl[j * 3 + k];
    __syncthreads();
    // result = M_0 * M_1 * ... * M_63 (order preserved: left * right)
    for (int s = 1; s < DEPTH; s <<= 1) {
        if ((t & (2 * s - 1)) == 0) {
            double a[9], b[9], c[9];
            #pragma unroll
            for (int i = 0; i < 9; ++i) { a[i] = M[t][i]; b[i] = M[t + s][i]; }
            #pragma unroll
            for (int i = 0; i < 3; ++i)
                #pragma unroll
                for (int j = 0; j < 3; ++j)
                    c[i * 3 + j] = a[i * 3 + 0] * b[0 * 3 + j]
                                 + a[i * 3 + 1] * b[1 * 3 + j]
                                 + a[i * 3 + 2] * b[2 * 3 + j];
            #pragma unroll
            for (int i = 0; i < 9; ++i) M[t][i] = c[i];
        }
        __syncthreads();
    }
    if (t < 9) P[t] = (float)M[0][t];   // out_j = sum_k x_k * P[k*3+j]
}

// ---- Kernel B: out[i] = x[i] @ P with LDS-staged coalescing ----
__global__ __launch_bounds__(BLOCK) void apply_chain(
        const float4* __restrict__ x4, float4* __restrict__ o4,
        const float* __restrict__ P) {
    __shared__ float4 s4[CHUNK];        // 12 KB
    const int tid = threadIdx.x;
    const long long base = (long long)blockIdx.x * CHUNK;

    // dense coalesced global->LDS (each wave instr: 64 lanes x 16B contiguous)
    #pragma unroll
    for (int k = 0; k < 3; ++k)
        s4[k * BLOCK + tid] = x4[base + k * BLOCK + tid];

    // wave-uniform scalar loads (overlap latency with staging)
    const float p00 = P[0], p01 = P[1], p02 = P[2];
    const float p10 = P[3], p11 = P[4], p12 = P[5];
    const float p20 = P[6], p21 = P[7], p22 = P[8];

    __syncthreads();

    // per-thread: 3 consecutive float4s = 4 rows (stride-12-word ds_read_b128,
    // 2-way bank aliasing per 16-lane phase -> free)
    float4 a = s4[3 * tid];
    float4 b = s4[3 * tid + 1];
    float4 c = s4[3 * tid + 2];

    // rows: r0=(a.x,a.y,a.z) r1=(a.w,b.x,b.y) r2=(b.z,b.w,c.x) r3=(c.y,c.z,c.w)
    float4 oa, ob, oc;
    oa.x = fmaf(a.x, p00, fmaf(a.y, p10, a.z * p20));
    oa.y = fmaf(a.x, p01, fmaf(a.y, p11, a.z * p21));
    oa.z = fmaf(a.x, p02, fmaf(a.y, p12, a.z * p22));
    oa.w = fmaf(a.w, p00, fmaf(b.x, p10, b.y * p20));
    ob.x = fmaf(a.w, p01, fmaf(b.x, p11, b.y * p21));
    ob.y = fmaf(a.w, p02, fmaf(b.x, p12, b.y * p22));
    ob.z = fmaf(b.z, p00, fmaf(b.w, p10, c.x * p20));
    ob.w = fmaf(b.z, p01, fmaf(b.w, p11, c.x * p21));
    oc.x = fmaf(b.z, p02, fmaf(b.w, p12, c.x * p22));
    oc.y = fmaf(c.y, p00, fmaf(c.z, p10, c.w * p20));
    oc.z = fmaf(c.y, p01, fmaf(c.z, p11, c.w * p21));
    oc.w = fmaf(c.y, p02, fmaf(c.z, p12, c.w * p22));

    s4[3 * tid]     = oa;
    s4[3 * tid + 1] = ob;
    s4[3 * tid + 2] = oc;

    __syncthreads();

    // dense coalesced LDS->global stores
    #pragma unroll
    for (int k = 0; k < 3; ++k)
        o4[base + k * BLOCK + tid] = s4[k * BLOCK + tid];
}

extern "C" void kernel_launch(void* const* d_in, const int* in_sizes, int n_in,
                              void* d_out, int out_size, void* d_ws, size_t ws_size,
                              hipStream_t stream) {
    const float* x = (const float*)d_in[0];
    const float* W = (const float*)d_in[1];
    float* out = (float*)d_out;
    float* P = (float*)d_ws;                   // 9 floats of scratch

    fold_weights<<<1, 64, 0, stream>>>(W, P);

    const long long n_floats = (long long)in_sizes[0];   // 25165824
    const long long n4 = n_floats / 4;                   // 6291456 float4s
    const int grid = (int)(n4 / CHUNK);                  // 8192 (exact fit)

    apply_chain<<<grid, BLOCK, 0, stream>>>(
        (const float4*)x, (float4*)out, P);
}